// Round 15
// baseline (649.751 us; speedup 1.0000x reference)
//
#include <hip/hip_runtime.h>
#include <math.h>

#define NB    512
#define NP    4096
#define BLOCK 256
#define KPT   4
#define CHUNK (BLOCK * KPT)     // 1024 points per block
#define NCHUNK (NP / CHUNK)     // 4 chunks per batch element

typedef float v2f __attribute__((ext_vector_type(2)));

// fp32 sin for layer 1, near-correctly-rounded (abs err ~2e-10 vs true):
// n in f32; one f64 fma reduction; Taylor-19 with the c13..c19 tail
// evaluated in f32 (tail weight x2^5*x^3 ~ 3e6 -> f32 tail rounding ~5e-17
// contributes ~1.5e-10 to sin; x 4e5 output gain = ~6e-5, invisible).
__device__ __forceinline__ float sin_cr(float tf) {
#pragma clang fp contract(off)
    float yf = tf * 0.15915494309189535f;
    float nf = rintf(yf);
    double n  = (double)nf;
    double t  = (double)tf;
    double x  = fma(n, -6.283185307179586, t);   // [-pi-3e-5, pi+3e-5]
    double x2 = x * x;
    float x2f = (float)x2;
    // f32 tail: S = c13 + x2*(c15 + x2*(c17 + x2*c19))
    float S = fmaf(x2f, -8.2206352466243297e-18f,  2.8114572543455206e-15f);
    S = fmaf(x2f, S, -7.6471637318198164e-13f);
    S = fmaf(x2f, S,  1.6059043836821613e-10f);
    // f64 head: Q = c3 + x2*(c5 + x2*(c7 + x2*(c9 + x2*(c11 + x2*S))))
    double P = (double)S;
    P = fma(x2, P, -1.0 / 39916800.0);   // c11
    P = fma(x2, P,  1.0 / 362880.0);     // c9
    P = fma(x2, P, -1.0 / 5040.0);       // c7
    P = fma(x2, P,  1.0 / 120.0);        // c5
    P = fma(x2, P, -1.0 / 6.0);          // c3
    double x3 = x2 * x;
    return (float)fma(P, x3, x);
}

// L2/L3 sin of 20*u (identical to R12/R14): y = u*(10/pi) revolutions,
// s = y - rint(y) in [-0.5,0.5] (exact), hardware v_sin_f32.
__device__ __forceinline__ v2f sin2_rev(v2f u) {
#pragma clang fp contract(off)
    v2f y = u * 3.1830988618379067f;     // 10/pi
    v2f n;
    n.x = rintf(y.x);
    n.y = rintf(y.y);
    v2f s = y - n;                        // exact
    v2f o;
    o.x = __builtin_amdgcn_sinf(s.x);
    o.y = __builtin_amdgcn_sinf(s.y);
    return o;
}

// n=20 dot, numpy column structure (stride-4 columns, tree (c0+c2)+(c1+c3)),
// fma-contracted (proven bit-safe at L2/L3/L4 in R10/R12/R14).
__device__ __forceinline__ v2f dot20_fma(const float* __restrict__ wr,
                                         const v2f* __restrict__ h) {
#pragma clang fp contract(fast)
    v2f c0 = h[0] * wr[0];
    v2f c1 = h[1] * wr[1];
    v2f c2 = h[2] * wr[2];
    v2f c3 = h[3] * wr[3];
    c0 = c0 + h[4]  * wr[4];   c1 = c1 + h[5]  * wr[5];
    c2 = c2 + h[6]  * wr[6];   c3 = c3 + h[7]  * wr[7];
    c0 = c0 + h[8]  * wr[8];   c1 = c1 + h[9]  * wr[9];
    c2 = c2 + h[10] * wr[10];  c3 = c3 + h[11] * wr[11];
    c0 = c0 + h[12] * wr[12];  c1 = c1 + h[13] * wr[13];
    c2 = c2 + h[14] * wr[14];  c3 = c3 + h[15] * wr[15];
    c0 = c0 + h[16] * wr[16];  c1 = c1 + h[17] * wr[17];
    c2 = c2 + h[18] * wr[18];  c3 = c3 + h[19] * wr[19];
    v2f s02 = c0 + c2;
    v2f s13 = c1 + c3;
    return s02 + s13;
}

// Param layout per batch (921 floats):
// [0,40) W1(20x2)  [40,60) b1 | [60,460) W2(20x20) [460,480) b2
// [480,880) W3(20x20) [880,900) b3 | [900,920) W4(1x20) [920] b4
// launch_bounds(256,6): cap VGPR at ~85 -> 6 waves/SIMD resident (was 5 at
// VGPR=96), tail round 33% fuller.
__global__ __launch_bounds__(BLOCK, 6) void siren20_npA_kernel(
    const float* __restrict__ coords,
    const float* __restrict__ wflat,
    float* __restrict__ out)
{
#pragma clang fp contract(off)
    __shared__ __align__(16) float w[928];
    const int b   = blockIdx.y;
    const int tid = threadIdx.x;
    const float* __restrict__ wg = wflat + (size_t)b * 921;

    #pragma unroll
    for (int k = 0; k < 4; ++k) {
        int i = tid + k * BLOCK;
        if (i < 921) w[i] = wg[i];
    }
    __syncthreads();

    const int p0 = blockIdx.x * CHUNK + tid;   // four coalesced points
    const float2* cbase = (const float2*)(coords + (size_t)b * NP * 2);
    const float2 cA0 = cbase[p0];
    const float2 cA1 = cbase[p0 + BLOCK];
    const float2 cB0 = cbase[p0 + 2 * BLOCK];
    const float2 cB1 = cbase[p0 + 3 * BLOCK];
    v2f cxA; cxA.x = cA0.x; cxA.y = cA1.x;
    v2f cyA; cyA.x = cA0.y; cyA.y = cA1.y;
    v2f cxB; cxB.x = cB0.x; cxB.y = cB1.x;
    v2f cyB; cyB.x = cB0.y; cyB.y = cB1.y;

    v2f hA[20], gA[20], hB[20], gB[20];

    // Layer 1: n=2 scalar dot (mul, add; no fma), +b, *20, near-CR sin.
    #pragma unroll
    for (int j = 0; j < 20; ++j) {
        const float w0 = w[2 * j], w1 = w[2 * j + 1], bb = w[40 + j];
        v2f sA = cxA * w0;
        sA = sA + cyA * w1;
        v2f uA = sA + bb;
        v2f tA = uA * 20.0f;
        hA[j].x = sin_cr(tA.x);
        hA[j].y = sin_cr(tA.y);
        v2f sB = cxB * w0;
        sB = sB + cyB * w1;
        v2f uB = sB + bb;
        v2f tB = uB * 20.0f;
        hB[j].x = sin_cr(tB.x);
        hB[j].y = sin_cr(tB.y);
    }

    // Layer 2: W at 60, b at 460 — two fma dots sharing weight loads (CSE)
    #pragma unroll
    for (int j = 0; j < 20; ++j) {
        const float* wr = &w[60 + 20 * j];
        v2f aA = dot20_fma(wr, hA);
        v2f aB = dot20_fma(wr, hB);
        const float bb = w[460 + j];
        gA[j] = sin2_rev(aA + bb);
        gB[j] = sin2_rev(aB + bb);
    }

    // Layer 3: W at 480, b at 880
    #pragma unroll
    for (int j = 0; j < 20; ++j) {
        const float* wr = &w[480 + 20 * j];
        v2f aA = dot20_fma(wr, gA);
        v2f aB = dot20_fma(wr, gB);
        const float bb = w[880 + j];
        hA[j] = sin2_rev(aA + bb);
        hB[j] = sin2_rev(aB + bb);
    }

    // Layer 4: W at 900, b at 920, clip
    {
        const float* wr = &w[900];
        v2f aA = dot20_fma(wr, hA);
        v2f aB = dot20_fma(wr, hB);
        const float bb = w[920];
        v2f uA = aA + bb;
        v2f uB = aB + bb;
        float* ob = out + (size_t)b * NP;
        ob[p0]             = fminf(fmaxf(uA.x, 0.0f), 1.0f);
        ob[p0 + BLOCK]     = fminf(fmaxf(uA.y, 0.0f), 1.0f);
        ob[p0 + 2 * BLOCK] = fminf(fmaxf(uB.x, 0.0f), 1.0f);
        ob[p0 + 3 * BLOCK] = fminf(fmaxf(uB.y, 0.0f), 1.0f);
    }
}

extern "C" void kernel_launch(void* const* d_in, const int* in_sizes, int n_in,
                              void* d_out, int out_size, void* d_ws, size_t ws_size,
                              hipStream_t stream) {
    const float* coords = (const float*)d_in[0];
    const float* wflat  = (const float*)d_in[1];
    float* out = (float*)d_out;
    dim3 grid(NCHUNK, NB);
    siren20_npA_kernel<<<grid, dim3(BLOCK), 0, stream>>>(coords, wflat, out);
}

// Round 16
// 68.700 us; speedup vs baseline: 9.4577x; 9.4577x over previous
//
#include <hip/hip_runtime.h>
#include <math.h>

#define NB    512
#define NP    4096
#define BLOCK 256
#define KPT   4
#define CHUNK (BLOCK * KPT)     // 1024 points per block
#define NCHUNK (NP / CHUNK)     // 4 chunks per batch element

typedef float v2f __attribute__((ext_vector_type(2)));

// fp32 sin for layer 1, near-correctly-rounded (abs err ~3e-10 vs true):
// n in f32; one f64 fma reduction; deg-19 Taylor with c11..c19 tail in f32
// (tail weight x2^4*x^3 ~ 3e5 -> f32 tail rounding ~8e-15 contributes
// ~2.4e-9 to sin; x ~1.2e5 output gain = ~3e-4, invisible).
__device__ __forceinline__ float sin_cr(float tf) {
#pragma clang fp contract(off)
    float yf = tf * 0.15915494309189535f;
    float nf = rintf(yf);
    double n  = (double)nf;
    double t  = (double)tf;
    double x  = fma(n, -6.283185307179586, t);   // [-pi-3e-5, pi+3e-5]
    double x2 = x * x;
    float x2f = (float)x2;
    // f32 tail: S = c11 + x2*(c13 + x2*(c15 + x2*(c17 + x2*c19)))
    float S = fmaf(x2f, -8.2206352466243297e-18f,  2.8114572543455206e-15f);
    S = fmaf(x2f, S, -7.6471637318198164e-13f);
    S = fmaf(x2f, S,  1.6059043836821613e-10f);
    S = fmaf(x2f, S, -2.5052108385441718e-8f);
    // f64 head: P = c3 + x2*(c5 + x2*(c7 + x2*(c9 + x2*S)))
    double P = (double)S;
    P = fma(x2, P,  1.0 / 362880.0);     // c9
    P = fma(x2, P, -1.0 / 5040.0);       // c7
    P = fma(x2, P,  1.0 / 120.0);        // c5
    P = fma(x2, P, -1.0 / 6.0);          // c3
    double x3 = x2 * x;
    return (float)fma(P, x3, x);
}

// L2/L3 sin of 20*u: y = u*(10/pi) revolutions; s = fract(y) in [0,1)
// (exact; same angle mod 1 rev as y - rint(y)); hardware v_sin_f32.
__device__ __forceinline__ v2f sin2_rev(v2f u) {
#pragma clang fp contract(off)
    v2f y = u * 3.1830988618379067f;     // 10/pi
    v2f o;
    o.x = __builtin_amdgcn_sinf(__builtin_amdgcn_fractf(y.x));
    o.y = __builtin_amdgcn_sinf(__builtin_amdgcn_fractf(y.y));
    return o;
}

// n=20 dot as a single fma chain with bias-init (acc = b; acc += w_i*h_i).
// 20 pk-fma, no column temps, no final tree, no separate bias add.
// Ordering noise ~2e-6 on L2/L3 args -> <=2.4e-3 at output (in budget).
// contract(fast) fuses mul+add into v_pk_fma_f32; no reassociation.
__device__ __forceinline__ v2f dot20_seq(const float* __restrict__ wr,
                                         const v2f* __restrict__ h,
                                         float bias) {
#pragma clang fp contract(fast)
    v2f acc; acc.x = bias; acc.y = bias;
    #pragma unroll
    for (int i = 0; i < 20; ++i)
        acc = acc + h[i] * wr[i];
    return acc;
}

// Param layout per batch (921 floats):
// [0,40) W1(20x2)  [40,60) b1 | [60,460) W2(20x20) [460,480) b2
// [480,880) W3(20x20) [880,900) b3 | [900,920) W4(1x20) [920] b4
__global__ __launch_bounds__(BLOCK) void siren20_npB_kernel(
    const float* __restrict__ coords,
    const float* __restrict__ wflat,
    float* __restrict__ out)
{
#pragma clang fp contract(off)
    __shared__ __align__(16) float w[928];
    const int b   = blockIdx.y;
    const int tid = threadIdx.x;
    const float* __restrict__ wg = wflat + (size_t)b * 921;

    #pragma unroll
    for (int k = 0; k < 4; ++k) {
        int i = tid + k * BLOCK;
        if (i < 921) w[i] = wg[i];
    }
    __syncthreads();

    const int p0 = blockIdx.x * CHUNK + tid;   // four coalesced points
    const float2* cbase = (const float2*)(coords + (size_t)b * NP * 2);
    const float2 cA0 = cbase[p0];
    const float2 cA1 = cbase[p0 + BLOCK];
    const float2 cB0 = cbase[p0 + 2 * BLOCK];
    const float2 cB1 = cbase[p0 + 3 * BLOCK];
    v2f cxA; cxA.x = cA0.x; cxA.y = cA1.x;
    v2f cyA; cyA.x = cA0.y; cyA.y = cA1.y;
    v2f cxB; cxB.x = cB0.x; cxB.y = cB1.x;
    v2f cyB; cyB.x = cB0.y; cyB.y = cB1.y;

    v2f hA[20], gA[20], hB[20], gB[20];

    // Layer 1: n=2 scalar dot (mul, add; no fma — exact numpy order),
    // +b, *20, near-CR sin. This path stays bit-frozen.
    #pragma unroll
    for (int j = 0; j < 20; ++j) {
        const float w0 = w[2 * j], w1 = w[2 * j + 1], bb = w[40 + j];
        v2f sA = cxA * w0;
        sA = sA + cyA * w1;
        v2f uA = sA + bb;
        v2f tA = uA * 20.0f;
        hA[j].x = sin_cr(tA.x);
        hA[j].y = sin_cr(tA.y);
        v2f sB = cxB * w0;
        sB = sB + cyB * w1;
        v2f uB = sB + bb;
        v2f tB = uB * 20.0f;
        hB[j].x = sin_cr(tB.x);
        hB[j].y = sin_cr(tB.y);
    }

    // Layer 2: W at 60, b at 460 — seq fma dots sharing weight loads
    #pragma unroll
    for (int j = 0; j < 20; ++j) {
        const float* wr = &w[60 + 20 * j];
        const float bb = w[460 + j];
        v2f aA = dot20_seq(wr, hA, bb);
        v2f aB = dot20_seq(wr, hB, bb);
        gA[j] = sin2_rev(aA);
        gB[j] = sin2_rev(aB);
    }

    // Layer 3: W at 480, b at 880
    #pragma unroll
    for (int j = 0; j < 20; ++j) {
        const float* wr = &w[480 + 20 * j];
        const float bb = w[880 + j];
        v2f aA = dot20_seq(wr, gA, bb);
        v2f aB = dot20_seq(wr, gB, bb);
        hA[j] = sin2_rev(aA);
        hB[j] = sin2_rev(aB);
    }

    // Layer 4: W at 900, b at 920, clip
    {
        const float* wr = &w[900];
        const float bb = w[920];
        v2f uA = dot20_seq(wr, hA, bb);
        v2f uB = dot20_seq(wr, hB, bb);
        float* ob = out + (size_t)b * NP;
        ob[p0]             = fminf(fmaxf(uA.x, 0.0f), 1.0f);
        ob[p0 + BLOCK]     = fminf(fmaxf(uA.y, 0.0f), 1.0f);
        ob[p0 + 2 * BLOCK] = fminf(fmaxf(uB.x, 0.0f), 1.0f);
        ob[p0 + 3 * BLOCK] = fminf(fmaxf(uB.y, 0.0f), 1.0f);
    }
}

extern "C" void kernel_launch(void* const* d_in, const int* in_sizes, int n_in,
                              void* d_out, int out_size, void* d_ws, size_t ws_size,
                              hipStream_t stream) {
    const float* coords = (const float*)d_in[0];
    const float* wflat  = (const float*)d_in[1];
    float* out = (float*)d_out;
    dim3 grid(NCHUNK, NB);
    siren20_npB_kernel<<<grid, dim3(BLOCK), 0, stream>>>(coords, wflat, out);
}